// Round 1
// baseline (680.984 us; speedup 1.0000x reference)
//
#include <hip/hip_runtime.h>
#include <hip/hip_fp16.h>

#define NROWS 8192
#define FIN   512
#define FOUT  256

using f16   = _Float16;
using f16x8 = __attribute__((ext_vector_type(8))) f16;
using f16x4 = __attribute__((ext_vector_type(4))) f16;
using f32x4 = __attribute__((ext_vector_type(4))) float;
using i32x4 = __attribute__((ext_vector_type(4))) int;

#define MFMA16(a, b, c) __builtin_amdgcn_mfma_f32_16x16x32_f16((a), (b), (c), 0, 0, 0)

// mish(x) = x * tanh(softplus(x)) = x * (t^2+2t)/(t^2+2t+2), t = e^x  (single exp)
__device__ __forceinline__ float mish_f(float x) {
  float t = __expf(x);
  float u = t * (t + 2.0f);
  return x * (u / (u + 2.0f));
}

__device__ __forceinline__ float dot4(float4 p, float4 q) {
  return p.x * q.x + p.y * q.y + p.z * q.z + p.w * q.w;
}

// ---------------------------------------------------------------------------
// K0: weight prep. wa1 = W @ a[:256], wa2 = W @ a[256:]; pack W into MFMA
// B-fragment layout as fp16 hi/lo. B-frag slot for value (k,f):
//   [(k>>5)*16 + (f>>4)]*64 + ((k>>3)&3)*16 + (f&15)] * 8 + (k&7)
__global__ __launch_bounds__(256) void k0_prep_w(
    const float* __restrict__ wgt, const float* __restrict__ a,
    f16* __restrict__ wB_hi, f16* __restrict__ wB_lo,
    float* __restrict__ wa1, float* __restrict__ wa2) {
  int k = blockIdx.x * 256 + threadIdx.x;
  if (k >= FIN) return;
  int kt = k >> 5, g2 = (k >> 3) & 3, e = k & 7;
  float acc1 = 0.f, acc2 = 0.f;
  for (int f = 0; f < FOUT; ++f) {
    float v = wgt[(size_t)k * FOUT + f];
    acc1 += v * a[f];
    acc2 += v * a[FOUT + f];
    f16 h = (f16)v;
    size_t base = (((size_t)(kt * 16 + (f >> 4)) * 64) + g2 * 16 + (f & 15)) * 8 + e;
    wB_hi[base] = h;
    wB_lo[base] = (f16)(v - (float)h);
  }
  wa1[k] = acc1;
  wa2[k] = acc2;
}

// ---------------------------------------------------------------------------
// K2: s_src = x @ wa1, s_dst = x @ wa2 (exact fp32; == h@a1 up to reassoc),
// plus global max of s_dst via order-preserving uint encoding + atomicMax.
__global__ __launch_bounds__(256) void k2_scores(
    const float* __restrict__ x, const float* __restrict__ wa1,
    const float* __restrict__ wa2, float* __restrict__ s_src,
    float* __restrict__ s_dst, unsigned int* __restrict__ maxd_enc) {
  int wv = threadIdx.x >> 6, lane = threadIdx.x & 63;
  int row = blockIdx.x * 4 + wv;
  const float4* xr = (const float4*)(x + (size_t)row * FIN);
  float4 x0 = xr[lane * 2], x1 = xr[lane * 2 + 1];
  const float4* w1 = (const float4*)wa1;
  const float4* w2 = (const float4*)wa2;
  float p1 = dot4(x0, w1[lane * 2]) + dot4(x1, w1[lane * 2 + 1]);
  float p2 = dot4(x0, w2[lane * 2]) + dot4(x1, w2[lane * 2 + 1]);
  for (int off = 32; off > 0; off >>= 1) {
    p1 += __shfl_down(p1, off);
    p2 += __shfl_down(p2, off);
  }
  if (lane == 0) {
    s_src[row] = p1;
    s_dst[row] = p2;
    unsigned b = __float_as_uint(p2);
    unsigned enc = (b & 0x80000000u) ? ~b : (b | 0x80000000u);
    atomicMax(maxd_enc, enc);
  }
}

// ---------------------------------------------------------------------------
// K1: h = x @ W via fp16 hi/lo 3-term split MFMA (error ~2^-21 rel).
// Output written directly in packed B-fragment layout (hi & lo fp16 arrays)
// for the main kernel's coalesced dwordx4 B loads.
// Block: 64(M) x 128(N) tile, 4 waves; wave w owns 32 cols (2 col-tiles).
__global__ __launch_bounds__(256) void k1_gemm_h(
    const float* __restrict__ x, const f16* __restrict__ wB_hi,
    const f16* __restrict__ wB_lo, f16* __restrict__ hB_hi,
    f16* __restrict__ hB_lo) {
  __shared__ float xs[64][36];  // +4 pad: 16B-aligned rows, 2-way bank alias (free)
  int mt = blockIdx.x >> 1, ns = blockIdx.x & 1;
  int m0 = mt * 64;
  int tid = threadIdx.x;
  int w = tid >> 6, lane = tid & 63;
  int g = lane >> 4, lr = lane & 15;

  f32x4 acc[4][2] = {};

  for (int kk = 0; kk < FIN; kk += 32) {
    {
      int r = tid >> 3;
      int c = (tid & 7) * 4;
      *(float4*)(&xs[r][c])      = *(const float4*)(x + (size_t)(m0 + r) * FIN + kk + c);
      *(float4*)(&xs[r + 32][c]) = *(const float4*)(x + (size_t)(m0 + r + 32) * FIN + kk + c);
    }
    __syncthreads();
    int kt = kk >> 5;
    f16x8 bh[2], bl[2];
#pragma unroll
    for (int ct = 0; ct < 2; ++ct) {
      int ft = ns * 8 + w * 2 + ct;
      size_t slot = ((size_t)(kt * 16 + ft) * 64 + lane) * 8;
      bh[ct] = *(const f16x8*)(wB_hi + slot);
      bl[ct] = *(const f16x8*)(wB_lo + slot);
    }
#pragma unroll
    for (int rt = 0; rt < 4; ++rt) {
      const float* ap = &xs[rt * 16 + lr][g * 8];
      f16x8 ah, al;
#pragma unroll
      for (int e = 0; e < 8; ++e) {
        float v = ap[e];
        f16 h = (f16)v;
        ah[e] = h;
        al[e] = (f16)(v - (float)h);
      }
#pragma unroll
      for (int ct = 0; ct < 2; ++ct) {
        acc[rt][ct] = MFMA16(ah, bh[ct], acc[rt][ct]);
        acc[rt][ct] = MFMA16(ah, bl[ct], acc[rt][ct]);
        acc[rt][ct] = MFMA16(al, bh[ct], acc[rt][ct]);
      }
    }
    __syncthreads();
  }

  // Epilogue: C/D frag (row=(lane>>4)*4+reg, col=lane&15) -> packed hi/lo.
  // Each lane's 4 regs land in one contiguous 8B half of a 16B frag slot.
#pragma unroll
  for (int rt = 0; rt < 4; ++rt) {
    int jg0 = m0 + rt * 16 + g * 4;
    int jt = jg0 >> 5, g2 = (jg0 >> 3) & 3, e0 = jg0 & 7;  // e0 in {0,4}
#pragma unroll
    for (int ct = 0; ct < 2; ++ct) {
      int f = ns * 128 + w * 32 + ct * 16 + lr;
      size_t base = (((size_t)(jt * 16 + (f >> 4)) * 64) + g2 * 16 + (f & 15)) * 8 + e0;
      f16x4 hv, lv;
#pragma unroll
      for (int rg = 0; rg < 4; ++rg) {
        float v = acc[rt][ct][rg];
        f16 h = (f16)v;
        hv[rg] = h;
        lv[rg] = (f16)(v - (float)h);
      }
      *(f16x4*)(hB_hi + base) = hv;
      *(f16x4*)(hB_lo + base) = lv;
    }
  }
}

// ---------------------------------------------------------------------------
// K3: fused masked softmax-weighted GEMM.
// Grid: 128 i-tiles (64 rows) x 8 j-chunks (1024 cols); jc = blockIdx&7 -> XCD
// affinity so the 1MB h-slice is L2-resident. P = adj ? exp(mish(s)-m_i) : 0
// with m_i = max(0, s_src[i]+max(s_dst)) so P in (0,1] (all normal fp16).
// Wave w generates the A-frag (P) for row-tile w, shares via LDS (dbuf,
// 1 barrier/step); Z via ones-B MFMA on the same fp16 P (consistency).
__global__ __launch_bounds__(256) void k3_attn(
    const int* __restrict__ adj, const f16* __restrict__ hB_hi,
    const f16* __restrict__ hB_lo, const float* __restrict__ s_src,
    const float* __restrict__ s_dst, const unsigned int* __restrict__ maxd_enc,
    float* __restrict__ num, float* __restrict__ Zbuf) {
  __shared__ float sd_lds[1024];
  __shared__ f16x8 pbuf[2][4][64];

  int it = blockIdx.x >> 3, jc = blockIdx.x & 7;
  int i0 = it * 64;
  int j0 = jc * 1024;
  int tid = threadIdx.x;
  int w = tid >> 6, lane = tid & 63;
  int g = lane >> 4, lr = lane & 15;

  *(float4*)(&sd_lds[tid * 4]) = *(const float4*)(s_dst + j0 + tid * 4);

  unsigned enc = *maxd_enc;
  float maxd = (enc & 0x80000000u) ? __uint_as_float(enc & 0x7fffffffu)
                                   : __uint_as_float(~enc);
  int ip = i0 + w * 16 + lr;
  float s_i = s_src[ip];
  float m_i = fmaxf(0.f, s_i + maxd);
  const int* adjrow = adj + (size_t)ip * NROWS + j0 + g * 8;

  __syncthreads();

  f32x4 acc[4][4] = {};
  f32x4 accz = {};
  f16x8 ones;
#pragma unroll
  for (int e = 0; e < 8; ++e) ones[e] = (f16)1.0f;

  i32x4 adjA = *(const i32x4*)(adjrow);
  i32x4 adjB = *(const i32x4*)(adjrow + 4);

  for (int st = 0; st < 32; ++st) {
    i32x4 nadjA = adjA, nadjB = adjB;
    if (st < 31) {  // prefetch next adj (HBM latency hiding)
      nadjA = *(const i32x4*)(adjrow + (st + 1) * 32);
      nadjB = *(const i32x4*)(adjrow + (st + 1) * 32 + 4);
    }
    float4 sd0 = *(const float4*)(&sd_lds[st * 32 + g * 8]);
    float4 sd1 = *(const float4*)(&sd_lds[st * 32 + g * 8 + 4]);
    float sdv[8] = {sd0.x, sd0.y, sd0.z, sd0.w, sd1.x, sd1.y, sd1.z, sd1.w};

    f16x8 pa;
#pragma unroll
    for (int e = 0; e < 8; ++e) {
      float s = s_i + sdv[e];
      float t = __expf(s);
      float u = t * (t + 2.0f);
      float sc = s * (u / (u + 2.0f));  // mish(s)
      float p = __expf(sc - m_i);
      int av = (e < 4) ? adjA[e] : adjB[e - 4];
      pa[e] = (av != 0) ? (f16)p : (f16)0.0f;
    }
    pbuf[st & 1][w][lane] = pa;
    accz = MFMA16(pa, ones, accz);
    __syncthreads();

    f16x8 afr[4];
#pragma unroll
    for (int rt = 0; rt < 4; ++rt) afr[rt] = pbuf[st & 1][rt][lane];

    int jt = jc * 32 + st;
#pragma unroll
    for (int ct = 0; ct < 4; ++ct) {
      int ft = w * 4 + ct;
      size_t slot = ((size_t)(jt * 16 + ft) * 64 + lane) * 8;
      f16x8 bhv = *(const f16x8*)(hB_hi + slot);
      f16x8 blv = *(const f16x8*)(hB_lo + slot);
#pragma unroll
      for (int rt = 0; rt < 4; ++rt) {
        acc[rt][ct] = MFMA16(afr[rt], bhv, acc[rt][ct]);
        acc[rt][ct] = MFMA16(afr[rt], blv, acc[rt][ct]);
      }
    }
    adjA = nadjA;
    adjB = nadjB;
  }

#pragma unroll
  for (int rt = 0; rt < 4; ++rt) {
    int ib = i0 + rt * 16 + g * 4;
#pragma unroll
    for (int ct = 0; ct < 4; ++ct) {
      int f = w * 64 + ct * 16 + lr;
#pragma unroll
      for (int rg = 0; rg < 4; ++rg)
        atomicAdd(&num[(size_t)(ib + rg) * FOUT + f], acc[rt][ct][rg]);
    }
  }
  if (lr == 0) {
    int ib = i0 + w * 16 + g * 4;
#pragma unroll
    for (int rg = 0; rg < 4; ++rg)
      atomicAdd(&Zbuf[ib + rg], accz[rg]);
  }
}

// ---------------------------------------------------------------------------
// K4: out = mish(num / Z), in place on d_out.
__global__ __launch_bounds__(256) void k4_final(float* __restrict__ out,
                                                const float* __restrict__ Zbuf) {
  int idx = blockIdx.x * 256 + threadIdx.x;  // one float4 per thread
  int row = idx >> 6;                        // 64 float4 per row of 256
  float rz = 1.0f / Zbuf[row];
  float4 v = *(float4*)(out + (size_t)idx * 4);
  v.x = mish_f(v.x * rz);
  v.y = mish_f(v.y * rz);
  v.z = mish_f(v.z * rz);
  v.w = mish_f(v.w * rz);
  *(float4*)(out + (size_t)idx * 4) = v;
}

// ---------------------------------------------------------------------------
extern "C" void kernel_launch(void* const* d_in, const int* in_sizes, int n_in,
                              void* d_out, int out_size, void* d_ws, size_t ws_size,
                              hipStream_t stream) {
  const float* x   = (const float*)d_in[0];
  const int*   adj = (const int*)d_in[1];
  const float* wgt = (const float*)d_in[2];
  const float* a   = (const float*)d_in[3];
  float* out = (float*)d_out;

  char* ws = (char*)d_ws;
  f16* hB_hi = (f16*)ws;                                  // 4 MB
  f16* hB_lo = (f16*)(ws + (4u << 20));                   // 4 MB
  f16* wB_hi = (f16*)(ws + (8u << 20));                   // 256 KB
  f16* wB_lo = (f16*)(ws + (8u << 20) + (256u << 10));    // 256 KB
  float* wa1   = (float*)(ws + (8u << 20) + (512u << 10));
  float* wa2   = wa1 + FIN;
  float* s_src = wa2 + FIN;
  float* s_dst = s_src + NROWS;
  float* Zbuf  = s_dst + NROWS;
  unsigned int* maxd = (unsigned int*)(Zbuf + NROWS);

  // d_out doubles as the fp32 numerator accumulator; Z + maxd zeroed too.
  hipMemsetAsync(d_out, 0, (size_t)out_size * sizeof(float), stream);
  hipMemsetAsync(Zbuf, 0, NROWS * sizeof(float) + sizeof(unsigned int), stream);

  k0_prep_w<<<2, 256, 0, stream>>>(wgt, a, wB_hi, wB_lo, wa1, wa2);
  k2_scores<<<NROWS / 4, 256, 0, stream>>>(x, wa1, wa2, s_src, s_dst, maxd);
  k1_gemm_h<<<(NROWS / 64) * 2, 256, 0, stream>>>(x, wB_hi, wB_lo, hB_hi, hB_lo);
  k3_attn<<<(NROWS / 64) * 8, 256, 0, stream>>>(adj, hB_hi, hB_lo, s_src, s_dst,
                                                maxd, out, Zbuf);
  k4_final<<<out_size / 4 / 256, 256, 0, stream>>>(out, Zbuf);
}